// Round 15
// baseline (5253.113 us; speedup 1.0000x reference)
//
#include <hip/hip_runtime.h>

// ---------------------------------------------------------------------------
// Sizes
// ---------------------------------------------------------------------------
#define BB 32
#define TT 1024
#define II 64
#define HH 512
#define FF 63
#define G4H 2048         // 4*H
#define KK 576           // H + I (concat [h | x])
#define MM 32768         // B*T
#define NW 32            // worker blocks (each owns 16 cells)

// out layout (elements): state[B,T,63] | reward[B,T] | hT[B,H] | cT[B,H]
#define RW_OFF 2064384
#define HT_OFF 2097152
#define CT_OFF 2113536

// ws layout (bytes) — total 47,540,864 (< proven 47.57 MB footprint)
#define WS_FLAGS   0            // u32[NW] @128-B stride: per-worker step counts
#define WS_EPOCH   4096         // u32[NW] @128-B stride: per-block epoch lines
#define WS_FLAG    8192         // u32 (1 = inputs are fp32)
#define WS_TICK    8320         // u32[8] per-XCD ticket counters
#define WS_CHOSEN  8384         // u32: 0 = undecided, else winning xcc+1
#define WS_BIASC   8448         // f32[2048]
#define WS_BSH     16640        // f32[512]
#define WS_BCSA    18688        // f32[512]   (bcsa|bcra contiguous)
#define WS_BCRA    20736        // f32[512]
#define WS_BCH     22784        // f32[64]
#define WS_SCAL    23040        // f32[2]: bv_sa, bv_ra
#define WS_VS      23168        // bf16[512]  (vs|vr contiguous)
#define WS_VR      24192        // bf16[512]
#define WS_ZB      25216        // f32[512] zeros
#define WS_H0      27264        // bf16[32][512]  (h0 slab)
#define WS_CP      60032        // bf16[32][512] (c0 converted)
#define WS_WHPAD   92800        // bf16[128][512]
#define WS_WHC     223872       // bf16[128][512] (combined heads)
#define WS_WSHT    354944       // bf16[512][512] (w_sh transposed)
#define WS_WSA     879232       // bf16[512][512]
#define WS_WRA     1403520      // bf16[512][512]
#define WS_WCSA    1927808      // bf16[512][512] (w_sa@w_sh) (wcsa|wcra contiguous)
#define WS_WCRA    2452096      // bf16[512][512] (w_ra@w_sh)
#define WS_WCAT    2976384      // bf16[2048][576]
#define WS_XP      5335680      // bf16[32][1024][64]
#define WS_ES      9529984      // f32[32768]  (es|er contiguous)
#define WS_ER      9661056      // f32[32768]
#define WS_PROJ    9792128      // bf16[32768][64]
#define WS_HX      13986432     // bf16[1024][32][512]: slab t = h(t), row t*32+b

typedef __bf16  bf16x8 __attribute__((ext_vector_type(8)));
typedef float   f32x4  __attribute__((ext_vector_type(4)));
typedef uint4 uint4a __attribute__((may_alias));
typedef unsigned int u32;

#define POLL_SENTINEL 0x7FFFFFFFu

__device__ __forceinline__ float bf2f(unsigned short u) {
    unsigned int v = ((unsigned int)u) << 16;
    return __builtin_bit_cast(float, v);
}
__device__ __forceinline__ unsigned short f2bf(float f) {
    unsigned int u = __builtin_bit_cast(unsigned int, f);
    u += 0x7fffu + ((u >> 16) & 1u);          // round to nearest even
    return (unsigned short)(u >> 16);
}
__device__ __forceinline__ bf16x8 ldb8(const unsigned short* p) {
    uint4 v = *(const uint4a*)p;
    return __builtin_bit_cast(bf16x8, v);
}
__device__ __forceinline__ float sigf(float x) { return 1.f / (1.f + __expf(-x)); }
__device__ __forceinline__ float tanhfast(float x) { return 1.f - 2.f / (__expf(2.f * x) + 1.f); }

// dual-dtype raw-input loaders (fl: 1 = underlying buffer is fp32)
__device__ __forceinline__ unsigned short loadu(const void* p, int i, int fl) {
    return fl ? f2bf(((const float*)p)[i]) : ((const unsigned short*)p)[i];
}
__device__ __forceinline__ float loadf(const void* p, int i, int fl) {
    return fl ? ((const float*)p)[i] : bf2f(((const unsigned short*)p)[i]);
}

// ---------------------------------------------------------------------------
// dtype sniff
// ---------------------------------------------------------------------------
__global__ void sniff_k(const unsigned short* __restrict__ xr, unsigned int* __restrict__ flag) {
    if (threadIdx.x == 0) {
        int cnt = 0;
        for (int i = 0; i < 256; ++i) {
            unsigned short u = xr[i];
            int e = (u >> 7) & 0xFF;
            if (u == 0 || (e >= 100 && e <= 140)) ++cnt;
        }
        *flag = (cnt < 220) ? 1u : 0u;
    }
}

// ---------------------------------------------------------------------------
// elementwise conversions into ws pools
// ---------------------------------------------------------------------------
__global__ void prep_all(const void* x, const void* h0, const void* c0,
                         const void* w_sh, const void* w_sa, const void* w_ra,
                         const void* w_st, const void* w_rw,
                         const void* v_sa, const void* v_ra,
                         const void* b_sh, const void* bv_sa, const void* bv_ra,
                         char* ws) {
    const int fl = (int)*(const unsigned int*)(ws + WS_FLAG);
    unsigned short* xp    = (unsigned short*)(ws + WS_XP);
    unsigned short* h0s   = (unsigned short*)(ws + WS_H0);
    unsigned short* cp    = (unsigned short*)(ws + WS_CP);
    unsigned short* wshT  = (unsigned short*)(ws + WS_WSHT);
    unsigned short* wsa   = (unsigned short*)(ws + WS_WSA);
    unsigned short* wra   = (unsigned short*)(ws + WS_WRA);
    unsigned short* whpad = (unsigned short*)(ws + WS_WHPAD);
    unsigned short* vs    = (unsigned short*)(ws + WS_VS);
    unsigned short* vr    = (unsigned short*)(ws + WS_VR);
    float* bsh  = (float*)(ws + WS_BSH);
    float* scal = (float*)(ws + WS_SCAL);
    float* zb   = (float*)(ws + WS_ZB);

    int gt = blockIdx.x * 256 + threadIdx.x;
    int gs = gridDim.x * 256;
    for (int i = gt; i < BB * TT * II; i += gs) xp[i] = loadu(x, i, fl);
    for (int i = gt; i < BB * HH; i += gs) { h0s[i] = loadu(h0, i, fl); cp[i] = loadu(c0, i, fl); }
    for (int i = gt; i < HH * HH; i += gs) {
        int m = i >> 9, k = i & 511;
        wshT[k * HH + m] = loadu(w_sh, i, fl);    // transpose
        wsa[i] = loadu(w_sa, i, fl);
        wra[i] = loadu(w_ra, i, fl);
    }
    for (int i = gt; i < 128 * HH; i += gs) {
        int f = i >> 9, k = i & 511;
        whpad[i] = (f < FF) ? loadu(w_st, f * HH + k, fl)
                 : (f == FF ? loadu(w_rw, k, fl) : (unsigned short)0);
    }
    for (int i = gt; i < HH; i += gs) {
        vs[i] = loadu(v_sa, i, fl); vr[i] = loadu(v_ra, i, fl);
        bsh[i] = loadf(b_sh, i, fl); zb[i] = 0.f;
    }
    if (gt == 0) { scal[0] = loadf(bv_sa, 0, fl); scal[1] = loadf(bv_ra, 0, fl); }
}

__global__ void prep_w(const void* __restrict__ w_hh, const void* __restrict__ w_ih,
                       const void* __restrict__ b_ih, const void* __restrict__ b_hh,
                       char* ws) {
    const int fl = (int)*(const unsigned int*)(ws + WS_FLAG);
    unsigned short* wcat = (unsigned short*)(ws + WS_WCAT);
    float* biasc = (float*)(ws + WS_BIASC);
    int c = blockIdx.x;   // [0,2048)
    for (int k = threadIdx.x; k < KK; k += 256)
        wcat[c * KK + k] = (k < HH) ? loadu(w_hh, c * HH + k, fl)
                                    : loadu(w_ih, c * II + (k - HH), fl);
    if (threadIdx.x == 0) biasc[c] = loadf(b_ih, c, fl) + loadf(b_hh, c, fl);
}

// combined biases: bc[j] = b2[j] + sum_k Wlhs[j,k] * b_sh[k]
__global__ void bias_comb(const void* b_sa, const void* b_ra,
                          const void* b_st, const void* b_rw, char* ws) {
    const int fl = (int)*(const unsigned int*)(ws + WS_FLAG);
    const float* bsh = (const float*)(ws + WS_BSH);
    int j = threadIdx.x;
    if (blockIdx.x == 0) {
        const unsigned short* w = (const unsigned short*)(ws + WS_WSA);
        float s = loadf(b_sa, j, fl);
        for (int k = 0; k < HH; ++k) s += bf2f(w[j * HH + k]) * bsh[k];
        ((float*)(ws + WS_BCSA))[j] = s;
    } else if (blockIdx.x == 1) {
        const unsigned short* w = (const unsigned short*)(ws + WS_WRA);
        float s = loadf(b_ra, j, fl);
        for (int k = 0; k < HH; ++k) s += bf2f(w[j * HH + k]) * bsh[k];
        ((float*)(ws + WS_BCRA))[j] = s;
    } else if (j < 64) {
        const unsigned short* w = (const unsigned short*)(ws + WS_WHPAD);
        float s = (j < FF) ? loadf(b_st, j, fl) : loadf(b_rw, 0, fl);
        for (int k = 0; k < HH; ++k) s += bf2f(w[j * HH + k]) * bsh[k];
        ((float*)(ws + WS_BCH))[j] = s;
    }
}

__global__ void init_e(char* ws) {
    const float* scal = (const float*)(ws + WS_SCAL);
    float* es = (float*)(ws + WS_ES);
    float* er = (float*)(ws + WS_ER);
    int i = blockIdx.x * 256 + threadIdx.x;
    if (i < MM) { es[i] = scal[0]; er[i] = scal[1]; }
}

// ---------------------------------------------------------------------------
// Persistent LSTM, single-XCD, signal-tree barrier (zero atomic fan-in):
// workers post flags[g]+=1 (sole poster, L2). ONLY block 0 polls the flags
// (lane j -> flag j: one poller per line). On all-ready it stores the epoch
// to 32 per-block lines; each block CAS-polls only ITS OWN epoch line
// (one poller per line). h exchange: t-major hx ring, plain stores/loads
// through the shared XCD L2 (proven R12). Watchdog + poison epoch (TT+2):
// failure mode is fast wrong output, never a hang.
// ---------------------------------------------------------------------------
__global__ __launch_bounds__(256, 1)
void lstm_k(char* __restrict__ ws, void* __restrict__ dout) {
    __shared__ float gbuf[32][68];
    __shared__ int s_slot;
    __shared__ int s_dead;

    u32* tick   = (u32*)(ws + WS_TICK);
    u32* chosen = (u32*)(ws + WS_CHOSEN);

    // ---- XCD claim ----
    if (threadIdx.x == 0) {
        u32 xcc;
        asm volatile("s_getreg_b32 %0, hwreg(HW_REG_XCC_ID)" : "=s"(xcc));
        xcc &= 7u;
        int slot = -1;
        u32 tk = __hip_atomic_fetch_add(&tick[xcc], 1u, __ATOMIC_RELAXED,
                                        __HIP_MEMORY_SCOPE_AGENT);
        if (tk < (u32)NW) {
            if (tk == (u32)NW - 1u) {
                u32 expected = 0u;
                __hip_atomic_compare_exchange_strong(chosen, &expected, xcc + 1u,
                    __ATOMIC_RELAXED, __ATOMIC_RELAXED, __HIP_MEMORY_SCOPE_AGENT);
            }
            u32 c = 0u;
            for (int it = 0; it < (1 << 20); ++it) {
                c = __hip_atomic_load(chosen, __ATOMIC_RELAXED, __HIP_MEMORY_SCOPE_AGENT);
                if (c != 0u) break;
                __builtin_amdgcn_s_sleep(8);
            }
            if (c == xcc + 1u) slot = (int)tk;
        }
        s_slot = slot;
        s_dead = 0;
    }
    __syncthreads();
    const int g = s_slot;
    if (g < 0) return;                          // not a worker

    const unsigned short* xp    = (const unsigned short*)(ws + WS_XP);
    const unsigned short* wcat  = (const unsigned short*)(ws + WS_WCAT);
    const float*          biasc = (const float*)(ws + WS_BIASC);
    const unsigned short* cinit = (const unsigned short*)(ws + WS_CP);
    const unsigned short* h0s   = (const unsigned short*)(ws + WS_H0);
    unsigned short*       hx    = (unsigned short*)(ws + WS_HX);
    u32*                  flags = (u32*)(ws + WS_FLAGS);
    u32*                  epoch = (u32*)(ws + WS_EPOCH);
    const int fl = (int)*(const unsigned int*)(ws + WS_FLAG);

    const int tid  = threadIdx.x;
    const int wave = tid >> 6, lane = tid & 63;
    const int quad = lane >> 4, l16 = lane & 15;
    const int mh = wave & 1, nh = wave >> 1;
    const int m = mh * 16 + l16;   // batch row for A frags

    // resident weight fragments: 2 n-tiles x 18 k-steps
    bf16x8 bw[2][18];
#pragma unroll
    for (int tn = 0; tn < 2; ++tn) {
        int nl   = nh * 32 + tn * 16 + l16;                 // local col [0,64)
        int gcol = (nl >> 4) * HH + g * 16 + (nl & 15);     // global gate col
        const unsigned short* wp = wcat + gcol * KK + quad * 8;
#pragma unroll
        for (int ks = 0; ks < 18; ++ks) bw[tn][ks] = ldb8(wp + ks * 32);
    }

    // epilogue: thread -> batch b, cell pair (cc, cc+1)
    const int b  = tid >> 3, pr = tid & 7, cc = pr * 2;
    const int n  = g * 16 + cc;                 // even global cell index
    const float bi0 = biasc[n],          bi1 = biasc[n + 1];
    const float bff0 = biasc[HH + n],    bff1 = biasc[HH + n + 1];
    const float bg0 = biasc[2*HH + n],   bg1 = biasc[2*HH + n + 1];
    const float bo0 = biasc[3*HH + n],   bo1 = biasc[3*HH + n + 1];
    float cst0 = bf2f(cinit[b * HH + n]);
    float cst1 = bf2f(cinit[b * HH + n + 1]);

    const unsigned short* xbase = xp + m * (TT * II) + quad * 8;
    bf16x8 ax0 = ldb8(xbase), ax1 = ldb8(xbase + 32);

    u32* myflag  = flags + g * 32;              // own 128-B flag line
    u32* aggp    = flags + (lane & 31) * 32;    // aggregator: lane j -> flag j
    u32* myepoch = epoch + g * 32;              // own 128-B epoch line

    for (int t = 0; t < TT; ++t) {
        // x prefetch for t+1 issued first
        int tn1 = (t + 1 < TT) ? t + 1 : t;
        bf16x8 axn0 = ldb8(xbase + tn1 * II);
        bf16x8 axn1 = ldb8(xbase + tn1 * II + 32);

        // ---- A-frags for h(t-1): plain loads (fresh addresses -> L1 miss
        //      -> probe of the XCD's shared L2 which holds the stores) ----
        const unsigned short* hrow =
            (t == 0 ? h0s : hx + (t - 1) * (BB * HH)) + m * HH + quad * 8;
        bf16x8 a[16];
#pragma unroll
        for (int i = 0; i < 16; ++i) a[i] = ldb8(hrow + i * 32);

        f32x4 acc0 = {0.f, 0.f, 0.f, 0.f}, acc1 = {0.f, 0.f, 0.f, 0.f};
#pragma unroll
        for (int i = 0; i < 16; ++i) {
            acc0 = __builtin_amdgcn_mfma_f32_16x16x32_bf16(a[i], bw[0][i], acc0, 0, 0, 0);
            acc1 = __builtin_amdgcn_mfma_f32_16x16x32_bf16(a[i], bw[1][i], acc1, 0, 0, 0);
        }
        acc0 = __builtin_amdgcn_mfma_f32_16x16x32_bf16(ax0, bw[0][16], acc0, 0, 0, 0);
        acc1 = __builtin_amdgcn_mfma_f32_16x16x32_bf16(ax0, bw[1][16], acc1, 0, 0, 0);
        acc0 = __builtin_amdgcn_mfma_f32_16x16x32_bf16(ax1, bw[0][17], acc0, 0, 0, 0);
        acc1 = __builtin_amdgcn_mfma_f32_16x16x32_bf16(ax1, bw[1][17], acc1, 0, 0, 0);

        // ---- C-frag -> LDS (row = batch, col = quad*16 + local cell) ----
        {
            int row = mh * 16 + quad * 4;
#pragma unroll
            for (int r = 0; r < 4; ++r) gbuf[row + r][nh * 32 + l16]      = acc0[r];
#pragma unroll
            for (int r = 0; r < 4; ++r) gbuf[row + r][nh * 32 + 16 + l16] = acc1[r];
        }
        __syncthreads();    // sync A: gbuf ready

        // ---- epilogue: 2 adjacent cells per thread, one u32 h-store ----
        {
            float2 giv = *(const float2*)&gbuf[b][cc];
            float2 gfv = *(const float2*)&gbuf[b][16 + cc];
            float2 ggv = *(const float2*)&gbuf[b][32 + cc];
            float2 gov = *(const float2*)&gbuf[b][48 + cc];
            cst0 = sigf(gfv.x + bff0) * cst0 + sigf(giv.x + bi0) * tanhfast(ggv.x + bg0);
            cst1 = sigf(gfv.y + bff1) * cst1 + sigf(giv.y + bi1) * tanhfast(ggv.y + bg1);
            float h0v = sigf(gov.x + bo0) * tanhfast(cst0);
            float h1v = sigf(gov.y + bo1) * tanhfast(cst1);
            u32 hp = (u32)f2bf(h0v) | ((u32)f2bf(h1v) << 16);
            *(u32*)&hx[t * (BB * HH) + b * HH + n] = hp;   // h(t) -> slab t
            if (t == TT - 1) {
                if (fl) {
                    ((float*)dout)[HT_OFF + b * HH + n]     = h0v;
                    ((float*)dout)[HT_OFF + b * HH + n + 1] = h1v;
                    ((float*)dout)[CT_OFF + b * HH + n]     = cst0;
                    ((float*)dout)[CT_OFF + b * HH + n + 1] = cst1;
                } else {
                    ((u32*)dout)[(HT_OFF + b * HH + n) >> 1] = hp;
                    ((u32*)dout)[(CT_OFF + b * HH + n) >> 1] =
                        (u32)f2bf(cst0) | ((u32)f2bf(cst1) << 16);
                }
            }
        }
        __syncthreads();    // sync B: drains (vmcnt 0) all waves' h stores

        // ---- post flag: sole poster, sole poller -> no queueing ----
        if (tid == 0)
            (void)__hip_atomic_fetch_add(myflag, 1u, __ATOMIC_RELAXED,
                                         __HIP_MEMORY_SCOPE_WORKGROUP);

        const u32 tgt = (u32)(t + 1);

        // ---- aggregator: block 0, wave 0 (lane j polls flag j only) ----
        if (g == 0 && wave == 0) {
            int trip = 0;
            for (int it = 0;; ++it) {
                u32 v = tgt;
                if (lane < 32) {
                    v = POLL_SENTINEL;
                    __hip_atomic_compare_exchange_strong(aggp, &v, POLL_SENTINEL,
                        __ATOMIC_RELAXED, __ATOMIC_RELAXED, __HIP_MEMORY_SCOPE_WORKGROUP);
                    if (v == POLL_SENTINEL) v = 0;
                }
                if (__all((int)(v >= tgt))) break;
                if (it > (1 << 16)) { trip = 1; break; }   // watchdog
            }
            u32 ev = trip ? (u32)(TT + 2) : tgt;
            if (lane < 32)
                __hip_atomic_store(epoch + lane * 32, ev, __ATOMIC_RELAXED,
                                   __HIP_MEMORY_SCOPE_WORKGROUP);
        }

        // ---- every block: poll ONLY its own epoch line (1 poller/line) ----
        if (tid == 0) {
            for (int it = 0;; ++it) {
                u32 v = POLL_SENTINEL;
                __hip_atomic_compare_exchange_strong(myepoch, &v, POLL_SENTINEL,
                    __ATOMIC_RELAXED, __ATOMIC_RELAXED, __HIP_MEMORY_SCOPE_WORKGROUP);
                if (v != POLL_SENTINEL && v >= tgt) {
                    if (v > (u32)TT) s_dead = 1;           // poison epoch
                    break;
                }
                if (it > (1 << 17)) { s_dead = 1; break; } // watchdog
            }
        }
        __syncthreads();    // sync C: release block
        if (s_dead) break;  // fail fast, never hang
        asm volatile("" ::: "memory");
        ax0 = axn0; ax1 = axn1;                 // rotate x prefetch
    }
}

// ---------------------------------------------------------------------------
// GEMM: C[M,N] = A[M,512](bf16) @ W[Wrows,512]^T(bf16) + bias
// EPI 0: write bf16 C.   EPI 2: fused e-epilogue over STACKED [wcsa|wcra]:
//   nb<8 -> atomicAdd(es[row], .) ; nb>=8 -> atomicAdd(er[row], .).
// A row index downstream of the LSTM is t*32+b (t-major hx ring).
// ---------------------------------------------------------------------------
template <int EPI>
__global__ __launch_bounds__(256)
void gemm_bt(const unsigned short* __restrict__ A,
             const unsigned short* __restrict__ W,
             const float* __restrict__ bias,
             void* __restrict__ Cv, int N,
             const unsigned short* __restrict__ vv,
             float* __restrict__ eout) {
    __shared__ unsigned short As[128][72];
    __shared__ unsigned short Bs[64][72];
    const int tid = threadIdx.x;
    const int wave = tid >> 6, lane = tid & 63, quad = lane >> 4, l16 = lane & 15;
    const int mb = blockIdx.x, nb = blockIdx.y;

    f32x4 acc[2][4];
#pragma unroll
    for (int tm = 0; tm < 2; ++tm)
#pragma unroll
        for (int tn = 0; tn < 4; ++tn) acc[tm][tn] = (f32x4){0.f, 0.f, 0.f, 0.f};

    for (int k0 = 0; k0 < 512; k0 += 64) {
#pragma unroll
        for (int i = 0; i < 4; ++i) {
            int v = tid + i * 256;
            int rowa = v >> 3, kc = (v & 7) * 8;
            *(uint4a*)&As[rowa][kc] = *(const uint4a*)(A + (mb * 128 + rowa) * 512 + k0 + kc);
        }
#pragma unroll
        for (int i = 0; i < 2; ++i) {
            int v = tid + i * 256;
            int rowb = v >> 3, kc = (v & 7) * 8;
            *(uint4a*)&Bs[rowb][kc] = *(const uint4a*)(W + (nb * 64 + rowb) * 512 + k0 + kc);
        }
        __syncthreads();
#pragma unroll
        for (int ks = 0; ks < 2; ++ks) {
            bf16x8 a0 = ldb8(&As[wave * 32 + l16][ks * 32 + quad * 8]);
            bf16x8 a1 = ldb8(&As[wave * 32 + 16 + l16][ks * 32 + quad * 8]);
#pragma unroll
            for (int tn = 0; tn < 4; ++tn) {
                bf16x8 bb = ldb8(&Bs[tn * 16 + l16][ks * 32 + quad * 8]);
                acc[0][tn] = __builtin_amdgcn_mfma_f32_16x16x32_bf16(a0, bb, acc[0][tn], 0, 0, 0);
                acc[1][tn] = __builtin_amdgcn_mfma_f32_16x16x32_bf16(a1, bb, acc[1][tn], 0, 0, 0);
            }
        }
        __syncthreads();
    }
    if (EPI == 0) {
#pragma unroll
        for (int tm = 0; tm < 2; ++tm)
#pragma unroll
            for (int tn = 0; tn < 4; ++tn)
#pragma unroll
                for (int r = 0; r < 4; ++r) {
                    int row = mb * 128 + wave * 32 + tm * 16 + quad * 4 + r;
                    int col = nb * 64 + tn * 16 + l16;
                    ((unsigned short*)Cv)[row * N + col] = f2bf(acc[tm][tn][r] + bias[col]);
                }
    } else {
        const int eoff = (nb >= 8) ? MM : 0;    // es | er (contiguous)
        float vcol[4], bcol[4];
#pragma unroll
        for (int tn = 0; tn < 4; ++tn) {
            int col = nb * 64 + tn * 16 + l16;
            vcol[tn] = bf2f(vv[col]); bcol[tn] = bias[col];
        }
#pragma unroll
        for (int tm = 0; tm < 2; ++tm)
#pragma unroll
            for (int r = 0; r < 4; ++r) {
                float s = 0.f;
#pragma unroll
                for (int tn = 0; tn < 4; ++tn)
                    s += vcol[tn] * tanhfast(acc[tm][tn][r] + bcol[tn]);
                s += __shfl_xor(s, 1); s += __shfl_xor(s, 2);
                s += __shfl_xor(s, 4); s += __shfl_xor(s, 8);
                if (l16 == 0) {
                    int row = mb * 128 + wave * 32 + tm * 16 + quad * 4 + r;
                    atomicAdd(&eout[eoff + row], s);
                }
            }
    }
}

// ---------------------------------------------------------------------------
// Online-softmax cumulative scan, software-pipelined.
// Reads row index t*32+b (t-major); writes original (b,t) layout.
// ---------------------------------------------------------------------------
__global__ __launch_bounds__(64)
void cumsum_k(char* __restrict__ ws, void* __restrict__ dout) {
    const unsigned short* proj = (const unsigned short*)(ws + WS_PROJ);
    const float* es = (const float*)(ws + WS_ES);
    const float* er = (const float*)(ws + WS_ER);
    const int fl = (int)*(const unsigned int*)(ws + WS_FLAG);
    const int b = blockIdx.x, lane = threadIdx.x;
    const bool isr = (lane == 63);
    float m_ = -3e38f, d_ = 0.f, n_ = 0.f;
    float pj = bf2f(proj[b * 64 + lane]);       // row t=0 -> index b
    float e  = isr ? er[b] : es[b];
    for (int t = 0; t < TT; ++t) {
        float pjn = 0.f, en = 0.f;
        if (t + 1 < TT) {                       // prefetch next row (t+1)*32+b
            int rn = (t + 1) * BB + b;
            pjn = bf2f(proj[rn * 64 + lane]);
            en  = isr ? er[rn] : es[rn];
        }
        float mn = fmaxf(m_, e);
        float al = __expf(m_ - mn);
        float p  = __expf(e - mn);
        d_ = d_ * al + p;
        n_ = n_ * al + p * pj;
        m_ = mn;
        float o = n_ / d_;
        int rout = b * TT + t;
        int addr = isr ? (RW_OFF + rout) : (rout * FF + lane);
        if (fl) ((float*)dout)[addr] = o;
        else    ((unsigned short*)dout)[addr] = f2bf(o);
        pj = pjn; e = en;
    }
}

// ---------------------------------------------------------------------------
extern "C" void kernel_launch(void* const* d_in, const int* in_sizes, int n_in,
                              void* d_out, int out_size, void* d_ws, size_t ws_size,
                              hipStream_t stream) {
    const void* x    = d_in[0];
    const void* h0   = d_in[2];
    const void* c0   = d_in[3];
    const void* w_ih = d_in[4];
    const void* w_hh = d_in[5];
    const void* b_ih = d_in[6];
    const void* b_hh = d_in[7];
    const void* w_sh = d_in[8];
    const void* b_sh = d_in[9];
    const void* w_sa = d_in[10];
    const void* b_sa = d_in[11];
    const void* v_sa = d_in[12];
    const void* bv_sa= d_in[13];
    const void* w_ra = d_in[14];
    const void* b_ra = d_in[15];
    const void* v_ra = d_in[16];
    const void* bv_ra= d_in[17];
    const void* w_st = d_in[18];
    const void* b_st = d_in[19];
    const void* w_rw = d_in[20];
    const void* b_rw = d_in[21];

    char* ws = (char*)d_ws;
    unsigned short* wsa   = (unsigned short*)(ws + WS_WSA);
    unsigned short* wra   = (unsigned short*)(ws + WS_WRA);
    unsigned short* whpad = (unsigned short*)(ws + WS_WHPAD);
    unsigned short* wshT  = (unsigned short*)(ws + WS_WSHT);
    unsigned short* wcsa  = (unsigned short*)(ws + WS_WCSA);
    unsigned short* wcra  = (unsigned short*)(ws + WS_WCRA);
    unsigned short* whc   = (unsigned short*)(ws + WS_WHC);
    unsigned short* routs = (unsigned short*)(ws + WS_HX);   // t-major h ring
    unsigned short* proj  = (unsigned short*)(ws + WS_PROJ);
    unsigned short* vs    = (unsigned short*)(ws + WS_VS);
    float* zb   = (float*)(ws + WS_ZB);
    float* bcsa = (float*)(ws + WS_BCSA);
    float* bch  = (float*)(ws + WS_BCH);
    float* es   = (float*)(ws + WS_ES);

    (void)hipMemsetAsync(d_ws, 0, 8448, stream);   // flags+epoch+dtype+tick/chosen
    sniff_k<<<1, 64, 0, stream>>>((const unsigned short*)x, (unsigned int*)(ws + WS_FLAG));
    prep_all<<<1024, 256, 0, stream>>>(x, h0, c0, w_sh, w_sa, w_ra, w_st, w_rw,
                                       v_sa, v_ra, b_sh, bv_sa, bv_ra, ws);
    prep_w<<<G4H, 256, 0, stream>>>(w_hh, w_ih, b_ih, b_hh, ws);
    init_e<<<MM / 256, 256, 0, stream>>>(ws);

    // sequential LSTM: 256 blocks, 32 on one XCD self-select as workers
    lstm_k<<<256, 256, 0, stream>>>(ws, d_out);

    // weight combines: wcomb = Wlhs @ w_sh  (A=Wlhs[M,512], W=w_sh^T[N=512,K=512])
    gemm_bt<0><<<dim3(4, 8), 256, 0, stream>>>(wsa,   wshT, zb, wcsa, 512, nullptr, nullptr);
    gemm_bt<0><<<dim3(4, 8), 256, 0, stream>>>(wra,   wshT, zb, wcra, 512, nullptr, nullptr);
    gemm_bt<0><<<dim3(1, 8), 256, 0, stream>>>(whpad, wshT, zb, whc,  512, nullptr, nullptr);
    bias_comb<<<3, 512, 0, stream>>>(b_sa, b_ra, b_st, b_rw, ws);

    // e_s AND e_r in one pass over stacked [wcsa|wcra] (A loaded once)
    gemm_bt<2><<<dim3(MM / 128, 16), 256, 0, stream>>>(routs, wcsa, bcsa, nullptr, 512, vs, es);
    // proj = routs @ whc^T + bch  (bf16, N=64)
    gemm_bt<0><<<dim3(MM / 128, 1), 256, 0, stream>>>(routs, whc, bch, proj, 64, nullptr, nullptr);
    // online-softmax causal scan -> state_outs + reward_outs
    cumsum_k<<<BB, 64, 0, stream>>>(ws, d_out);
}

// Round 16
// 4634.426 us; speedup vs baseline: 1.1335x; 1.1335x over previous
//
#include <hip/hip_runtime.h>

// ---------------------------------------------------------------------------
// Sizes
// ---------------------------------------------------------------------------
#define BB 32
#define TT 1024
#define II 64
#define HH 512
#define FF 63
#define G4H 2048         // 4*H
#define KK 576           // H + I (concat [h | x])
#define MM 32768         // B*T
#define NW 32            // worker blocks (each owns 16 cells)

// out layout (elements): state[B,T,63] | reward[B,T] | hT[B,H] | cT[B,H]
#define RW_OFF 2064384
#define HT_OFF 2097152
#define CT_OFF 2113536

// ws layout (bytes)
#define WS_FLAGS   0            // u32[NW] @128-B stride: per-worker step counts
#define WS_FLAG    4096         // u32 (1 = inputs are fp32)
#define WS_TICK    4224         // u32[8] per-XCD ticket counters
#define WS_CHOSEN  4288         // u32: 0 = undecided, else winning xcc+1
#define WS_BIASC   8448         // f32[2048]
#define WS_BSH     16640        // f32[512]
#define WS_BCSA    18688        // f32[512]   (bcsa|bcra contiguous)
#define WS_BCRA    20736        // f32[512]
#define WS_BCH     22784        // f32[64]
#define WS_SCAL    23040        // f32[2]: bv_sa, bv_ra
#define WS_VS      23168        // bf16[512]  (vs|vr contiguous)
#define WS_VR      24192        // bf16[512]
#define WS_ZB      25216        // f32[512] zeros
#define WS_H0      27264        // bf16[32][512]  (h0 slab)
#define WS_CP      60032        // bf16[32][512] (c0 converted)
#define WS_WHPAD   92800        // bf16[128][512]
#define WS_WHC     223872       // bf16[128][512] (combined heads)
#define WS_WSHT    354944       // bf16[512][512] (w_sh transposed)
#define WS_WSA     879232       // bf16[512][512]
#define WS_WRA     1403520      // bf16[512][512]
#define WS_WCSA    1927808      // bf16[512][512] (w_sa@w_sh) (wcsa|wcra contiguous)
#define WS_WCRA    2452096      // bf16[512][512] (w_ra@w_sh)
#define WS_WCAT    2976384      // bf16[2048][576]
#define WS_XP      5335680      // bf16[32][1024][64]
#define WS_ES      9529984      // f32[32768]  (es|er contiguous)
#define WS_ER      9661056      // f32[32768]
#define WS_PROJ    9792128      // bf16[32768][64]
#define WS_HX      13986432     // bf16[1024][32][512]: slab t = h(t), row t*32+b

typedef __bf16  bf16x8 __attribute__((ext_vector_type(8)));
typedef float   f32x4  __attribute__((ext_vector_type(4)));
typedef uint4 uint4a __attribute__((may_alias));
typedef unsigned int u32;

__device__ __forceinline__ float bf2f(unsigned short u) {
    unsigned int v = ((unsigned int)u) << 16;
    return __builtin_bit_cast(float, v);
}
__device__ __forceinline__ unsigned short f2bf(float f) {
    unsigned int u = __builtin_bit_cast(unsigned int, f);
    u += 0x7fffu + ((u >> 16) & 1u);          // round to nearest even
    return (unsigned short)(u >> 16);
}
__device__ __forceinline__ bf16x8 ldb8(const unsigned short* p) {
    uint4 v = *(const uint4a*)p;
    return __builtin_bit_cast(bf16x8, v);
}
__device__ __forceinline__ float sigf(float x) { return 1.f / (1.f + __expf(-x)); }
__device__ __forceinline__ float tanhfast(float x) { return 1.f - 2.f / (__expf(2.f * x) + 1.f); }

// dual-dtype raw-input loaders (fl: 1 = underlying buffer is fp32)
__device__ __forceinline__ unsigned short loadu(const void* p, int i, int fl) {
    return fl ? f2bf(((const float*)p)[i]) : ((const unsigned short*)p)[i];
}
__device__ __forceinline__ float loadf(const void* p, int i, int fl) {
    return fl ? ((const float*)p)[i] : bf2f(((const unsigned short*)p)[i]);
}

// ---------------------------------------------------------------------------
// dtype sniff
// ---------------------------------------------------------------------------
__global__ void sniff_k(const unsigned short* __restrict__ xr, unsigned int* __restrict__ flag) {
    if (threadIdx.x == 0) {
        int cnt = 0;
        for (int i = 0; i < 256; ++i) {
            unsigned short u = xr[i];
            int e = (u >> 7) & 0xFF;
            if (u == 0 || (e >= 100 && e <= 140)) ++cnt;
        }
        *flag = (cnt < 220) ? 1u : 0u;
    }
}

// ---------------------------------------------------------------------------
// elementwise conversions into ws pools
// ---------------------------------------------------------------------------
__global__ void prep_all(const void* x, const void* h0, const void* c0,
                         const void* w_sh, const void* w_sa, const void* w_ra,
                         const void* w_st, const void* w_rw,
                         const void* v_sa, const void* v_ra,
                         const void* b_sh, const void* bv_sa, const void* bv_ra,
                         char* ws) {
    const int fl = (int)*(const unsigned int*)(ws + WS_FLAG);
    unsigned short* xp    = (unsigned short*)(ws + WS_XP);
    unsigned short* h0s   = (unsigned short*)(ws + WS_H0);
    unsigned short* cp    = (unsigned short*)(ws + WS_CP);
    unsigned short* wshT  = (unsigned short*)(ws + WS_WSHT);
    unsigned short* wsa   = (unsigned short*)(ws + WS_WSA);
    unsigned short* wra   = (unsigned short*)(ws + WS_WRA);
    unsigned short* whpad = (unsigned short*)(ws + WS_WHPAD);
    unsigned short* vs    = (unsigned short*)(ws + WS_VS);
    unsigned short* vr    = (unsigned short*)(ws + WS_VR);
    float* bsh  = (float*)(ws + WS_BSH);
    float* scal = (float*)(ws + WS_SCAL);
    float* zb   = (float*)(ws + WS_ZB);

    int gt = blockIdx.x * 256 + threadIdx.x;
    int gs = gridDim.x * 256;
    for (int i = gt; i < BB * TT * II; i += gs) xp[i] = loadu(x, i, fl);
    for (int i = gt; i < BB * HH; i += gs) { h0s[i] = loadu(h0, i, fl); cp[i] = loadu(c0, i, fl); }
    for (int i = gt; i < HH * HH; i += gs) {
        int m = i >> 9, k = i & 511;
        wshT[k * HH + m] = loadu(w_sh, i, fl);    // transpose
        wsa[i] = loadu(w_sa, i, fl);
        wra[i] = loadu(w_ra, i, fl);
    }
    for (int i = gt; i < 128 * HH; i += gs) {
        int f = i >> 9, k = i & 511;
        whpad[i] = (f < FF) ? loadu(w_st, f * HH + k, fl)
                 : (f == FF ? loadu(w_rw, k, fl) : (unsigned short)0);
    }
    for (int i = gt; i < HH; i += gs) {
        vs[i] = loadu(v_sa, i, fl); vr[i] = loadu(v_ra, i, fl);
        bsh[i] = loadf(b_sh, i, fl); zb[i] = 0.f;
    }
    if (gt == 0) { scal[0] = loadf(bv_sa, 0, fl); scal[1] = loadf(bv_ra, 0, fl); }
}

__global__ void prep_w(const void* __restrict__ w_hh, const void* __restrict__ w_ih,
                       const void* __restrict__ b_ih, const void* __restrict__ b_hh,
                       char* ws) {
    const int fl = (int)*(const unsigned int*)(ws + WS_FLAG);
    unsigned short* wcat = (unsigned short*)(ws + WS_WCAT);
    float* biasc = (float*)(ws + WS_BIASC);
    int c = blockIdx.x;   // [0,2048)
    for (int k = threadIdx.x; k < KK; k += 256)
        wcat[c * KK + k] = (k < HH) ? loadu(w_hh, c * HH + k, fl)
                                    : loadu(w_ih, c * II + (k - HH), fl);
    if (threadIdx.x == 0) biasc[c] = loadf(b_ih, c, fl) + loadf(b_hh, c, fl);
}

// combined biases: bc[j] = b2[j] + sum_k Wlhs[j,k] * b_sh[k]
__global__ void bias_comb(const void* b_sa, const void* b_ra,
                          const void* b_st, const void* b_rw, char* ws) {
    const int fl = (int)*(const unsigned int*)(ws + WS_FLAG);
    const float* bsh = (const float*)(ws + WS_BSH);
    int j = threadIdx.x;
    if (blockIdx.x == 0) {
        const unsigned short* w = (const unsigned short*)(ws + WS_WSA);
        float s = loadf(b_sa, j, fl);
        for (int k = 0; k < HH; ++k) s += bf2f(w[j * HH + k]) * bsh[k];
        ((float*)(ws + WS_BCSA))[j] = s;
    } else if (blockIdx.x == 1) {
        const unsigned short* w = (const unsigned short*)(ws + WS_WRA);
        float s = loadf(b_ra, j, fl);
        for (int k = 0; k < HH; ++k) s += bf2f(w[j * HH + k]) * bsh[k];
        ((float*)(ws + WS_BCRA))[j] = s;
    } else if (j < 64) {
        const unsigned short* w = (const unsigned short*)(ws + WS_WHPAD);
        float s = (j < FF) ? loadf(b_st, j, fl) : loadf(b_rw, 0, fl);
        for (int k = 0; k < HH; ++k) s += bf2f(w[j * HH + k]) * bsh[k];
        ((float*)(ws + WS_BCH))[j] = s;
    }
}

__global__ void init_e(char* ws) {
    const float* scal = (const float*)(ws + WS_SCAL);
    float* es = (float*)(ws + WS_ES);
    float* er = (float*)(ws + WS_ER);
    int i = blockIdx.x * 256 + threadIdx.x;
    if (i < MM) { es[i] = scal[0]; er[i] = scal[1]; }
}

// ---------------------------------------------------------------------------
// Persistent LSTM, single-XCD (R12-proven structure). 256 blocks; each
// tickets its XCD (HW_REG_XCC_ID); first XCD to collect 32 wins; losers
// exit. All 32 workers share one L2:
//  - h exchange through t-major ring hx (addresses never reused -> plain
//    write-through stores land in shared L2; plain loads always L1-miss and
//    probe that same L2).
//  - flags: post = fetch_add RMW (executes in L2); poll = agent-scope
//    RELAXED atomic loads (sc1: bypass L1, read L2 fresh — no CAS
//    exclusive-access cost).  Watchdog + poison flag: fail fast, never hang.
// ---------------------------------------------------------------------------
__global__ __launch_bounds__(256, 1)
void lstm_k(char* __restrict__ ws, void* __restrict__ dout) {
    __shared__ float gbuf[32][68];
    __shared__ int s_slot;
    __shared__ int s_dead;

    u32* tick   = (u32*)(ws + WS_TICK);
    u32* chosen = (u32*)(ws + WS_CHOSEN);

    // ---- XCD claim ----
    if (threadIdx.x == 0) {
        u32 xcc;
        asm volatile("s_getreg_b32 %0, hwreg(HW_REG_XCC_ID)" : "=s"(xcc));
        xcc &= 7u;
        int slot = -1;
        u32 tk = __hip_atomic_fetch_add(&tick[xcc], 1u, __ATOMIC_RELAXED,
                                        __HIP_MEMORY_SCOPE_AGENT);
        if (tk < (u32)NW) {
            if (tk == (u32)NW - 1u) {
                u32 expected = 0u;
                __hip_atomic_compare_exchange_strong(chosen, &expected, xcc + 1u,
                    __ATOMIC_RELAXED, __ATOMIC_RELAXED, __HIP_MEMORY_SCOPE_AGENT);
            }
            u32 c = 0u;
            for (int it = 0; it < (1 << 20); ++it) {
                c = __hip_atomic_load(chosen, __ATOMIC_RELAXED, __HIP_MEMORY_SCOPE_AGENT);
                if (c != 0u) break;
                __builtin_amdgcn_s_sleep(8);
            }
            if (c == xcc + 1u) slot = (int)tk;
        }
        s_slot = slot;
        s_dead = 0;
    }
    __syncthreads();
    const int g = s_slot;
    if (g < 0) return;                          // not a worker

    const unsigned short* xp    = (const unsigned short*)(ws + WS_XP);
    const unsigned short* wcat  = (const unsigned short*)(ws + WS_WCAT);
    const float*          biasc = (const float*)(ws + WS_BIASC);
    const unsigned short* cinit = (const unsigned short*)(ws + WS_CP);
    const unsigned short* h0s   = (const unsigned short*)(ws + WS_H0);
    unsigned short*       hx    = (unsigned short*)(ws + WS_HX);
    u32*                  flags = (u32*)(ws + WS_FLAGS);
    const int fl = (int)*(const unsigned int*)(ws + WS_FLAG);

    const int tid  = threadIdx.x;
    const int wave = tid >> 6, lane = tid & 63;
    const int quad = lane >> 4, l16 = lane & 15;
    const int mh = wave & 1, nh = wave >> 1;
    const int m = mh * 16 + l16;   // batch row for A frags

    // resident weight fragments: 2 n-tiles x 18 k-steps
    bf16x8 bw[2][18];
#pragma unroll
    for (int tn = 0; tn < 2; ++tn) {
        int nl   = nh * 32 + tn * 16 + l16;                 // local col [0,64)
        int gcol = (nl >> 4) * HH + g * 16 + (nl & 15);     // global gate col
        const unsigned short* wp = wcat + gcol * KK + quad * 8;
#pragma unroll
        for (int ks = 0; ks < 18; ++ks) bw[tn][ks] = ldb8(wp + ks * 32);
    }

    // epilogue: thread -> batch b, cell pair (cc, cc+1)
    const int b  = tid >> 3, pr = tid & 7, cc = pr * 2;
    const int n  = g * 16 + cc;                 // even global cell index
    const float bi0 = biasc[n],          bi1 = biasc[n + 1];
    const float bff0 = biasc[HH + n],    bff1 = biasc[HH + n + 1];
    const float bg0 = biasc[2*HH + n],   bg1 = biasc[2*HH + n + 1];
    const float bo0 = biasc[3*HH + n],   bo1 = biasc[3*HH + n + 1];
    float cst0 = bf2f(cinit[b * HH + n]);
    float cst1 = bf2f(cinit[b * HH + n + 1]);

    const unsigned short* xbase = xp + m * (TT * II) + quad * 8;
    bf16x8 ax0 = ldb8(xbase), ax1 = ldb8(xbase + 32);

    u32* myflag = flags + g * 32;               // own 128-B flag line
    u32* pollp  = flags + (lane & 31) * 32;     // lane j -> block j's line

    for (int t = 0; t < TT; ++t) {
        // x prefetch for t+1 issued first
        int tn1 = (t + 1 < TT) ? t + 1 : t;
        bf16x8 axn0 = ldb8(xbase + tn1 * II);
        bf16x8 axn1 = ldb8(xbase + tn1 * II + 32);

        // ---- A-frags for h(t-1): plain loads (fresh addresses -> L1 miss
        //      -> probe of the XCD's shared L2 which holds the stores) ----
        const unsigned short* hrow =
            (t == 0 ? h0s : hx + (t - 1) * (BB * HH)) + m * HH + quad * 8;
        bf16x8 a[16];
#pragma unroll
        for (int i = 0; i < 16; ++i) a[i] = ldb8(hrow + i * 32);

        f32x4 acc0 = {0.f, 0.f, 0.f, 0.f}, acc1 = {0.f, 0.f, 0.f, 0.f};
#pragma unroll
        for (int i = 0; i < 16; ++i) {
            acc0 = __builtin_amdgcn_mfma_f32_16x16x32_bf16(a[i], bw[0][i], acc0, 0, 0, 0);
            acc1 = __builtin_amdgcn_mfma_f32_16x16x32_bf16(a[i], bw[1][i], acc1, 0, 0, 0);
        }
        acc0 = __builtin_amdgcn_mfma_f32_16x16x32_bf16(ax0, bw[0][16], acc0, 0, 0, 0);
        acc1 = __builtin_amdgcn_mfma_f32_16x16x32_bf16(ax0, bw[1][16], acc1, 0, 0, 0);
        acc0 = __builtin_amdgcn_mfma_f32_16x16x32_bf16(ax1, bw[0][17], acc0, 0, 0, 0);
        acc1 = __builtin_amdgcn_mfma_f32_16x16x32_bf16(ax1, bw[1][17], acc1, 0, 0, 0);

        // ---- C-frag -> LDS (row = batch, col = quad*16 + local cell) ----
        {
            int row = mh * 16 + quad * 4;
#pragma unroll
            for (int r = 0; r < 4; ++r) gbuf[row + r][nh * 32 + l16]      = acc0[r];
#pragma unroll
            for (int r = 0; r < 4; ++r) gbuf[row + r][nh * 32 + 16 + l16] = acc1[r];
        }
        __syncthreads();    // sync A: gbuf ready

        // ---- epilogue: 2 adjacent cells per thread, one u32 h-store ----
        {
            float2 giv = *(const float2*)&gbuf[b][cc];
            float2 gfv = *(const float2*)&gbuf[b][16 + cc];
            float2 ggv = *(const float2*)&gbuf[b][32 + cc];
            float2 gov = *(const float2*)&gbuf[b][48 + cc];
            cst0 = sigf(gfv.x + bff0) * cst0 + sigf(giv.x + bi0) * tanhfast(ggv.x + bg0);
            cst1 = sigf(gfv.y + bff1) * cst1 + sigf(giv.y + bi1) * tanhfast(ggv.y + bg1);
            float h0v = sigf(gov.x + bo0) * tanhfast(cst0);
            float h1v = sigf(gov.y + bo1) * tanhfast(cst1);
            u32 hp = (u32)f2bf(h0v) | ((u32)f2bf(h1v) << 16);
            *(u32*)&hx[t * (BB * HH) + b * HH + n] = hp;   // h(t) -> slab t
            if (t == TT - 1) {
                if (fl) {
                    ((float*)dout)[HT_OFF + b * HH + n]     = h0v;
                    ((float*)dout)[HT_OFF + b * HH + n + 1] = h1v;
                    ((float*)dout)[CT_OFF + b * HH + n]     = cst0;
                    ((float*)dout)[CT_OFF + b * HH + n + 1] = cst1;
                } else {
                    ((u32*)dout)[(HT_OFF + b * HH + n) >> 1] = hp;
                    ((u32*)dout)[(CT_OFF + b * HH + n) >> 1] =
                        (u32)f2bf(cst0) | ((u32)f2bf(cst1) << 16);
                }
            }
        }
        __syncthreads();    // sync B: drains (vmcnt 0) all waves' h stores

        // ---- post flag: real RMW (+1), executes in the shared L2 ----
        if (tid == 0)
            (void)__hip_atomic_fetch_add(myflag, 1u, __ATOMIC_RELAXED,
                                         __HIP_MEMORY_SCOPE_WORKGROUP);

        // ---- wave 0 polls all 32 flags via sc1 loads (L1-bypass) ----
        if (wave == 0) {
            u32 tgt = (u32)(t + 1);
            int trip = 0;
            for (int it = 0;; ++it) {
                u32 v = (lane < 32)
                    ? __hip_atomic_load(pollp, __ATOMIC_RELAXED, __HIP_MEMORY_SCOPE_AGENT)
                    : tgt;
                if (__all((int)(v >= tgt))) break;
                if (it > (1 << 17)) { trip = 1; break; }   // watchdog
            }
            if (trip && lane == 0) {
                __hip_atomic_store(myflag, (u32)(TT + 2), __ATOMIC_RELAXED,
                                   __HIP_MEMORY_SCOPE_AGENT);   // free peers
                s_dead = 1;
            }
        }
        __syncthreads();    // sync C: release block
        if (s_dead) break;  // fail fast, never hang
        asm volatile("" ::: "memory");
        ax0 = axn0; ax1 = axn1;                 // rotate x prefetch
    }
}

// ---------------------------------------------------------------------------
// GEMM: C[M,N] = A[M,512](bf16) @ W[Wrows,512]^T(bf16) + bias
// EPI 0: write bf16 C.   EPI 2: fused e-epilogue over STACKED [wcsa|wcra]:
//   nb<8 -> atomicAdd(es[row], .) ; nb>=8 -> atomicAdd(er[row], .).
// A row index downstream of the LSTM is t*32+b (t-major hx ring).
// ---------------------------------------------------------------------------
template <int EPI>
__global__ __launch_bounds__(256)
void gemm_bt(const unsigned short* __restrict__ A,
             const unsigned short* __restrict__ W,
             const float* __restrict__ bias,
             void* __restrict__ Cv, int N,
             const unsigned short* __restrict__ vv,
             float* __restrict__ eout) {
    __shared__ unsigned short As[128][72];
    __shared__ unsigned short Bs[64][72];
    const int tid = threadIdx.x;
    const int wave = tid >> 6, lane = tid & 63, quad = lane >> 4, l16 = lane & 15;
    const int mb = blockIdx.x, nb = blockIdx.y;

    f32x4 acc[2][4];
#pragma unroll
    for (int tm = 0; tm < 2; ++tm)
#pragma unroll
        for (int tn = 0; tn < 4; ++tn) acc[tm][tn] = (f32x4){0.f, 0.f, 0.f, 0.f};

    for (int k0 = 0; k0 < 512; k0 += 64) {
#pragma unroll
        for (int i = 0; i < 4; ++i) {
            int v = tid + i * 256;
            int rowa = v >> 3, kc = (v & 7) * 8;
            *(uint4a*)&As[rowa][kc] = *(const uint4a*)(A + (mb * 128 + rowa) * 512 + k0 + kc);
        }
#pragma unroll
        for (int i = 0; i < 2; ++i) {
            int v = tid + i * 256;
            int rowb = v >> 3, kc = (v & 7) * 8;
            *(uint4a*)&Bs[rowb][kc] = *(const uint4a*)(W + (nb * 64 + rowb) * 512 + k0 + kc);
        }
        __syncthreads();
#pragma unroll
        for (int ks = 0; ks < 2; ++ks) {
            bf16x8 a0 = ldb8(&As[wave * 32 + l16][ks * 32 + quad * 8]);
            bf16x8 a1 = ldb8(&As[wave * 32 + 16 + l16][ks * 32 + quad * 8]);
#pragma unroll
            for (int tn = 0; tn < 4; ++tn) {
                bf16x8 bb = ldb8(&Bs[tn * 16 + l16][ks * 32 + quad * 8]);
                acc[0][tn] = __builtin_amdgcn_mfma_f32_16x16x32_bf16(a0, bb, acc[0][tn], 0, 0, 0);
                acc[1][tn] = __builtin_amdgcn_mfma_f32_16x16x32_bf16(a1, bb, acc[1][tn], 0, 0, 0);
            }
        }
        __syncthreads();
    }
    if (EPI == 0) {
#pragma unroll
        for (int tm = 0; tm < 2; ++tm)
#pragma unroll
            for (int tn = 0; tn < 4; ++tn)
#pragma unroll
                for (int r = 0; r < 4; ++r) {
                    int row = mb * 128 + wave * 32 + tm * 16 + quad * 4 + r;
                    int col = nb * 64 + tn * 16 + l16;
                    ((unsigned short*)Cv)[row * N + col] = f2bf(acc[tm][tn][r] + bias[col]);
                }
    } else {
        const int eoff = (nb >= 8) ? MM : 0;    // es | er (contiguous)
        float vcol[4], bcol[4];
#pragma unroll
        for (int tn = 0; tn < 4; ++tn) {
            int col = nb * 64 + tn * 16 + l16;
            vcol[tn] = bf2f(vv[col]); bcol[tn] = bias[col];
        }
#pragma unroll
        for (int tm = 0; tm < 2; ++tm)
#pragma unroll
            for (int r = 0; r < 4; ++r) {
                float s = 0.f;
#pragma unroll
                for (int tn = 0; tn < 4; ++tn)
                    s += vcol[tn] * tanhfast(acc[tm][tn][r] + bcol[tn]);
                s += __shfl_xor(s, 1); s += __shfl_xor(s, 2);
                s += __shfl_xor(s, 4); s += __shfl_xor(s, 8);
                if (l16 == 0) {
                    int row = mb * 128 + wave * 32 + tm * 16 + quad * 4 + r;
                    atomicAdd(&eout[eoff + row], s);
                }
            }
    }
}

// ---------------------------------------------------------------------------
// Online-softmax cumulative scan, software-pipelined.
// Reads row index t*32+b (t-major); writes original (b,t) layout.
// ---------------------------------------------------------------------------
__global__ __launch_bounds__(64)
void cumsum_k(char* __restrict__ ws, void* __restrict__ dout) {
    const unsigned short* proj = (const unsigned short*)(ws + WS_PROJ);
    const float* es = (const float*)(ws + WS_ES);
    const float* er = (const float*)(ws + WS_ER);
    const int fl = (int)*(const unsigned int*)(ws + WS_FLAG);
    const int b = blockIdx.x, lane = threadIdx.x;
    const bool isr = (lane == 63);
    float m_ = -3e38f, d_ = 0.f, n_ = 0.f;
    float pj = bf2f(proj[b * 64 + lane]);       // row t=0 -> index b
    float e  = isr ? er[b] : es[b];
    for (int t = 0; t < TT; ++t) {
        float pjn = 0.f, en = 0.f;
        if (t + 1 < TT) {                       // prefetch next row (t+1)*32+b
            int rn = (t + 1) * BB + b;
            pjn = bf2f(proj[rn * 64 + lane]);
            en  = isr ? er[rn] : es[rn];
        }
        float mn = fmaxf(m_, e);
        float al = __expf(m_ - mn);
        float p  = __expf(e - mn);
        d_ = d_ * al + p;
        n_ = n_ * al + p * pj;
        m_ = mn;
        float o = n_ / d_;
        int rout = b * TT + t;
        int addr = isr ? (RW_OFF + rout) : (rout * FF + lane);
        if (fl) ((float*)dout)[addr] = o;
        else    ((unsigned short*)dout)[addr] = f2bf(o);
        pj = pjn; e = en;
    }
}

// ---------------------------------------------------------------------------
extern "C" void kernel_launch(void* const* d_in, const int* in_sizes, int n_in,
                              void* d_out, int out_size, void* d_ws, size_t ws_size,
                              hipStream_t stream) {
    const void* x    = d_in[0];
    const void* h0   = d_in[2];
    const void* c0   = d_in[3];
    const void* w_ih = d_in[4];
    const void* w_hh = d_in[5];
    const void* b_ih = d_in[6];
    const void* b_hh = d_in[7];
    const void* w_sh = d_in[8];
    const void* b_sh = d_in[9];
    const void* w_sa = d_in[10];
    const void* b_sa = d_in[11];
    const void* v_sa = d_in[12];
    const void* bv_sa= d_in[13];
    const void* w_ra = d_in[14];
    const void* b_ra = d_in[15];
    const void* v_ra = d_in[16];
    const void* bv_ra= d_in[17];
    const void* w_st = d_in[18];
    const void* b_st = d_in[19];
    const void* w_rw = d_in[20];
    const void* b_rw = d_in[21];

    char* ws = (char*)d_ws;
    unsigned short* wsa   = (unsigned short*)(ws + WS_WSA);
    unsigned short* wra   = (unsigned short*)(ws + WS_WRA);
    unsigned short* whpad = (unsigned short*)(ws + WS_WHPAD);
    unsigned short* wshT  = (unsigned short*)(ws + WS_WSHT);
    unsigned short* wcsa  = (unsigned short*)(ws + WS_WCSA);
    unsigned short* wcra  = (unsigned short*)(ws + WS_WCRA);
    unsigned short* whc   = (unsigned short*)(ws + WS_WHC);
    unsigned short* routs = (unsigned short*)(ws + WS_HX);   // t-major h ring
    unsigned short* proj  = (unsigned short*)(ws + WS_PROJ);
    unsigned short* vs    = (unsigned short*)(ws + WS_VS);
    float* zb   = (float*)(ws + WS_ZB);
    float* bcsa = (float*)(ws + WS_BCSA);
    float* bch  = (float*)(ws + WS_BCH);
    float* es   = (float*)(ws + WS_ES);

    (void)hipMemsetAsync(d_ws, 0, 8448, stream);   // flags + dtype + tick/chosen
    sniff_k<<<1, 64, 0, stream>>>((const unsigned short*)x, (unsigned int*)(ws + WS_FLAG));
    prep_all<<<1024, 256, 0, stream>>>(x, h0, c0, w_sh, w_sa, w_ra, w_st, w_rw,
                                       v_sa, v_ra, b_sh, bv_sa, bv_ra, ws);
    prep_w<<<G4H, 256, 0, stream>>>(w_hh, w_ih, b_ih, b_hh, ws);
    init_e<<<MM / 256, 256, 0, stream>>>(ws);

    // sequential LSTM: 256 blocks, 32 on one XCD self-select as workers
    lstm_k<<<256, 256, 0, stream>>>(ws, d_out);

    // weight combines: wcomb = Wlhs @ w_sh  (A=Wlhs[M,512], W=w_sh^T[N=512,K=512])
    gemm_bt<0><<<dim3(4, 8), 256, 0, stream>>>(wsa,   wshT, zb, wcsa, 512, nullptr, nullptr);
    gemm_bt<0><<<dim3(4, 8), 256, 0, stream>>>(wra,   wshT, zb, wcra, 512, nullptr, nullptr);
    gemm_bt<0><<<dim3(1, 8), 256, 0, stream>>>(whpad, wshT, zb, whc,  512, nullptr, nullptr);
    bias_comb<<<3, 512, 0, stream>>>(b_sa, b_ra, b_st, b_rw, ws);

    // e_s AND e_r in one pass over stacked [wcsa|wcra] (A loaded once)
    gemm_bt<2><<<dim3(MM / 128, 16), 256, 0, stream>>>(routs, wcsa, bcsa, nullptr, 512, vs, es);
    // proj = routs @ whc^T + bch  (bf16, N=64)
    gemm_bt<0><<<dim3(MM / 128, 1), 256, 0, stream>>>(routs, whc, bch, proj, 64, nullptr, nullptr);
    // online-softmax causal scan -> state_outs + reward_outs
    cumsum_k<<<BB, 64, 0, stream>>>(ws, d_out);
}